// Round 10
// baseline (242.866 us; speedup 1.0000x reference)
//
#include <hip/hip_runtime.h>
#include <hip/hip_bf16.h>

#define QUERY_DIM 128
#define HIDDEN 128

typedef float f32x4 __attribute__((ext_vector_type(4)));

__device__ __forceinline__ float dot4(f32x4 a, f32x4 b) {
    return a.x * b.x + a.y * b.y + a.z * b.z + a.w * b.w;
}

// ---------------------------------------------------------------------------
// Kernel 1: W[e][d] = sum_h WQ[h][e] * WK[h][d]   (128x128, trivial)
// ---------------------------------------------------------------------------
__global__ void wqk_kernel(const float* __restrict__ WQ,
                           const float* __restrict__ WK,
                           float* __restrict__ W) {
    int e = blockIdx.x;    // 0..127
    int d = threadIdx.x;   // 0..127
    float acc = 0.f;
#pragma unroll 8
    for (int h = 0; h < HIDDEN; ++h) {
        acc += WQ[h * QUERY_DIM + e] * WK[h * 128 + d];
    }
    W[e * 128 + d] = acc;
}

// ---------------------------------------------------------------------------
// Kernel 2 (mega): block b owns segments 8b..8b+7 (contiguous ~1MB K region).
//  Phase S (threads 0..8, overlapped): binary-search segment boundaries.
//  Phase A: R rows 8b..8b+7 computed in-block (W staged in 32KB halves,
//           exactly the old qproj scheme) -> rbuf in LDS. R never hits HBM.
//  Phase B: per wave, stream 2 segments: double-buffered 8-key batches
//           (8x1KB NT loads in flight), online max/sum, then weights pass
//           from L1-hot scores.
// LDS = 32K(wl) + 4K(ql) + 4K(rbuf) + 36B ~= 40KB -> 4 blocks/CU.
// ---------------------------------------------------------------------------
__global__ __launch_bounds__(256) void mega_kernel(const float* __restrict__ Q,
                                                   const float* __restrict__ W,
                                                   const float* __restrict__ K,
                                                   const int* __restrict__ idx,
                                                   float* __restrict__ weights,
                                                   float* scores,   // no restrict: store+load alias
                                                   int nmols, int total) {
    __shared__ float wl[64 * 128];   // 32 KB: half of W
    __shared__ float ql[8 * 128];    // 4 KB: 8 query rows
    __shared__ float rbuf[8 * 128];  // 4 KB: 8 R rows
    __shared__ int   segb[9];

    const int t = threadIdx.x;
    const long row0 = (long)blockIdx.x * 8;   // first segment of this block

    // ---- phase S: 9 boundary searches (threads 0..8), overlaps staging ----
    if (t < 9) {
        int m = (int)row0 + t;
        if (m >= nmols) {
            segb[t] = total;
        } else {
            int lo = 0, hi = total;
            while (lo < hi) {
                int mid = (lo + hi) >> 1;
                if (idx[mid] < m) lo = mid + 1; else hi = mid;
            }
            segb[t] = lo;
        }
    }

    // ---- stage 8 Q rows: 1024 floats = 256 threads x f32x4 ----
    {
        long qmax = (long)nmols * 128 - 4;
        long qoff = row0 * 128 + t * 4;
        if (qoff > qmax) qoff = qmax;           // clamp (unused rows)
        *(f32x4*)&ql[t * 4] = *(const f32x4*)&Q[qoff];
    }

    // ---- phase A: R rows (qproj scheme, 8 rows over 256 threads) ----
    const int c = t & 127;
    const int g = t >> 7;                        // 0..1 -> rows g*4..g*4+3
    float acc[4] = {0.f, 0.f, 0.f, 0.f};

    for (int hf = 0; hf < 2; ++hf) {
        __syncthreads();
        for (int i = t * 4; i < 64 * 128; i += 256 * 4) {
            *(f32x4*)&wl[i] = *(const f32x4*)&W[hf * 64 * 128 + i];
        }
        __syncthreads();
        for (int d = 0; d < 64; d += 4) {
            float w0 = wl[(d + 0) * 128 + c];
            float w1 = wl[(d + 1) * 128 + c];
            float w2 = wl[(d + 2) * 128 + c];
            float w3 = wl[(d + 3) * 128 + c];
            int dg = hf * 64 + d;
#pragma unroll
            for (int r = 0; r < 4; ++r) {
                f32x4 q = *(const f32x4*)&ql[(g * 4 + r) * 128 + dg];
                acc[r] += q.x * w0 + q.y * w1 + q.z * w2 + q.w * w3;
            }
        }
    }
#pragma unroll
    for (int r = 0; r < 4; ++r) rbuf[(g * 4 + r) * 128 + c] = acc[r];
    __syncthreads();   // rbuf + segb ready

    // ---- phase B: per-wave segment streaming (R8 pipeline) ----
    const int lane = t & 63;
    const int hw = lane >> 5;        // half-wave 0/1
    const int hl = lane & 31;        // lane within half-wave
    const int wv = t >> 6;           // wave in block 0..3
    const float sc = 0.08838834764831845f;  // 1/sqrt(128)

    for (int si = 0; si < 2; ++si) {
        int ls = wv * 2 + si;                 // local segment 0..7
        long s = row0 + ls;
        if (s >= nmols) break;
        int s0 = segb[ls], s1 = segb[ls + 1];
        if (s0 >= s1) continue;

        f32x4 rfrag = *(const f32x4*)&rbuf[ls * 128 + hl * 4];

        float mx = -__builtin_inff();
        float sum = 0.f;
        int kb = s0;

        f32x4 a0, a1, a2, a3;
        bool have = (kb + 8 <= s1);
        if (have) {
            long k = kb + hw;                  // rows k, k+2, k+4, k+6
            a0 = __builtin_nontemporal_load((const f32x4*)(K + (k + 0) * 128) + hl);
            a1 = __builtin_nontemporal_load((const f32x4*)(K + (k + 2) * 128) + hl);
            a2 = __builtin_nontemporal_load((const f32x4*)(K + (k + 4) * 128) + hl);
            a3 = __builtin_nontemporal_load((const f32x4*)(K + (k + 6) * 128) + hl);
        }
        while (have) {
            bool havenext = (kb + 16 <= s1);
            f32x4 b0, b1, b2, b3;
            if (havenext) {                    // issue next batch NOW
                long kn = kb + 8 + hw;
                b0 = __builtin_nontemporal_load((const f32x4*)(K + (kn + 0) * 128) + hl);
                b1 = __builtin_nontemporal_load((const f32x4*)(K + (kn + 2) * 128) + hl);
                b2 = __builtin_nontemporal_load((const f32x4*)(K + (kn + 4) * 128) + hl);
                b3 = __builtin_nontemporal_load((const f32x4*)(K + (kn + 6) * 128) + hl);
            }
            float v0 = dot4(a0, rfrag);
            float v1 = dot4(a1, rfrag);
            float v2 = dot4(a2, rfrag);
            float v3 = dot4(a3, rfrag);
#pragma unroll
            for (int off = 16; off > 0; off >>= 1) {
                v0 += __shfl_xor(v0, off, 64);
                v1 += __shfl_xor(v1, off, 64);
                v2 += __shfl_xor(v2, off, 64);
                v3 += __shfl_xor(v3, off, 64);
            }
            v0 *= sc; v1 *= sc; v2 *= sc; v3 *= sc;
            long k = kb + hw;
            if (hl == 0) {
                scores[k + 0] = v0;
                scores[k + 2] = v1;
                scores[k + 4] = v2;
                scores[k + 6] = v3;
            }
            float bm = fmaxf(fmaxf(v0, v1), fmaxf(v2, v3));
            float nm = fmaxf(mx, bm);
            sum = sum * __expf(mx - nm)
                + __expf(v0 - nm) + __expf(v1 - nm)
                + __expf(v2 - nm) + __expf(v3 - nm);
            mx = nm;
            kb += 8;
            a0 = b0; a1 = b1; a2 = b2; a3 = b3;
            have = havenext;
        }
        for (long k = kb + hw; k < s1; k += 2) {   // tail (<8 keys)
            f32x4 kv = __builtin_nontemporal_load((const f32x4*)(K + k * 128) + hl);
            float v = dot4(kv, rfrag);
#pragma unroll
            for (int off = 16; off > 0; off >>= 1) v += __shfl_xor(v, off, 64);
            v *= sc;
            if (hl == 0) scores[k] = v;
            float nm = fmaxf(mx, v);
            sum = sum * __expf(mx - nm) + __expf(v - nm);
            mx = nm;
        }
        // combine the two half-waves' (mx,sum)
        float mo = __shfl_xor(mx, 32, 64);
        float so = __shfl_xor(sum, 32, 64);
        float nm = fmaxf(mx, mo);
        sum = sum * __expf(mx - nm) + so * __expf(mo - nm);
        mx = nm;
        float inv = 1.0f / sum;

        // make this wave's score stores visible before re-reading
        asm volatile("s_waitcnt vmcnt(0)" ::: "memory");

        // weights from L1-hot scores
        for (int i = s0 + lane; i < s1; i += 64)
            weights[i] = __expf(scores[i] - mx) * inv;
    }
}

// ---------------------------------------------------------------------------
extern "C" void kernel_launch(void* const* d_in, const int* in_sizes, int n_in,
                              void* d_out, int out_size, void* d_ws, size_t ws_size,
                              hipStream_t stream) {
    const float* Q   = (const float*)d_in[0];
    const float* K   = (const float*)d_in[1];
    const float* WQ  = (const float*)d_in[2];
    const float* WK  = (const float*)d_in[3];
    const int*   idx = (const int*)d_in[4];

    const int nmols = in_sizes[0] / QUERY_DIM;   // 16384
    const int total = in_sizes[4];               // 1048576

    float* weights = (float*)d_out;              // output 0
    float* scores  = (float*)d_out + total;      // output 1

    float* W = (float*)d_ws;                     // 64 KB scratch

    wqk_kernel<<<128, 128, 0, stream>>>(WQ, WK, W);
    int blocks = (nmols + 7) / 8;                // 2048
    mega_kernel<<<blocks, 256, 0, stream>>>(Q, W, K, idx, weights, scores, nmols, total);
}

// Round 11
// 158.499 us; speedup vs baseline: 1.5323x; 1.5323x over previous
//
#include <hip/hip_runtime.h>
#include <hip/hip_bf16.h>

#define QUERY_DIM 128
#define HIDDEN 128

typedef float f32x4 __attribute__((ext_vector_type(4)));

__device__ __forceinline__ float dot4(f32x4 a, f32x4 b) {
    return a.x * b.x + a.y * b.y + a.z * b.z + a.w * b.w;
}

// ---------------------------------------------------------------------------
// Kernel 1 (combo): blocks 0..63  -> W[e][d] = sum_h WQ[h][e]*WK[h][d]
//                   blocks 64..   -> segment starts via binary search
// ---------------------------------------------------------------------------
__global__ __launch_bounds__(256) void combo_kernel(const float* __restrict__ WQ,
                                                    const float* __restrict__ WK,
                                                    float* __restrict__ W,
                                                    const int* __restrict__ idx,
                                                    int* __restrict__ start,
                                                    int nmols, int total) {
    int b = blockIdx.x;
    int t = threadIdx.x;
    if (b < 64) {
        int e = b * 2 + (t >> 7);   // 0..127
        int d = t & 127;
        float acc = 0.f;
#pragma unroll 8
        for (int h = 0; h < HIDDEN; ++h) {
            acc += WQ[h * QUERY_DIM + e] * WK[h * 128 + d];
        }
        W[e * 128 + d] = acc;
    } else {
        int m = (b - 64) * 256 + t;
        if (m > nmols) return;
        if (m == nmols) { start[m] = total; return; }
        int lo = 0, hi = total;
        while (lo < hi) {
            int mid = (lo + hi) >> 1;
            if (idx[mid] < m) lo = mid + 1; else hi = mid;
        }
        start[m] = lo;
    }
}

// ---------------------------------------------------------------------------
// Kernel 2 (fused2, dominant): wave w owns segments 2w, 2w+1.
//  Step 1: compute BOTH R rows in registers from L2-resident W (64KB shared
//          by all waves): per 4-d group, 2 uniform-broadcast q loads (16B)
//          + 4 W-row f32x4 loads + 32 FMA. No LDS, no syncthreads, no
//          occupancy cost -> R never exists in HBM, qproj dispatch deleted.
//  Step 2: R8 streaming pipeline per segment: double-buffered 8-key batches
//          (8x1KB NT loads in flight), online max/sum, weights from L1-hot
//          scores.
// ---------------------------------------------------------------------------
__global__ __launch_bounds__(256) void fused2_kernel(const float* __restrict__ Q,
                                                     const float* __restrict__ W,
                                                     const float* __restrict__ K,
                                                     const int* __restrict__ start,
                                                     float* __restrict__ weights,
                                                     float* scores,   // no restrict: store+load alias
                                                     int nmols, int total) {
    const int t = threadIdx.x;
    const int lane = t & 63;
    const int hw = lane >> 5;        // half-wave 0/1
    const int hl = lane & 31;        // lane within half-wave
    const long wave = (blockIdx.x * 256 + t) >> 6;
    const float sc = 0.08838834764831845f;  // 1/sqrt(128)

    long sA = wave * 2;
    if (sA >= nmols) return;
    long sB = sA + 1;
    long sBc = sB < nmols ? sB : sA;            // clamped for safe q load
    int b0 = start[sA];
    int b1 = start[sA + 1];
    int b2 = start[sB < nmols ? sB + 1 : sB];   // start[16384]=total is valid

    // ---- step 1: rfrag for both segments, in registers ----
    f32x4 r0 = {0.f, 0.f, 0.f, 0.f};
    f32x4 r1 = {0.f, 0.f, 0.f, 0.f};
    {
        const float* q0 = Q + sA * 128;
        const float* q1 = Q + sBc * 128;
#pragma unroll 8
        for (int d = 0; d < 128; d += 4) {
            f32x4 qv0 = *(const f32x4*)(q0 + d);          // uniform 16B broadcast
            f32x4 qv1 = *(const f32x4*)(q1 + d);
            const float* wp = W + (long)d * 128 + hl * 4;
            f32x4 w0 = *(const f32x4*)(wp);
            f32x4 w1 = *(const f32x4*)(wp + 128);
            f32x4 w2 = *(const f32x4*)(wp + 256);
            f32x4 w3 = *(const f32x4*)(wp + 384);
            r0 += qv0.x * w0 + qv0.y * w1 + qv0.z * w2 + qv0.w * w3;
            r1 += qv1.x * w0 + qv1.y * w1 + qv1.z * w2 + qv1.w * w3;
        }
    }

    // ---- step 2: stream the two segments (R8 pipeline) ----
    for (int si = 0; si < 2; ++si) {
        long s = sA + si;
        if (s >= nmols) break;
        int s0 = si ? b1 : b0;
        int s1 = si ? b2 : b1;
        if (s0 >= s1) continue;
        f32x4 rfrag = si ? r1 : r0;

        float mx = -__builtin_inff();
        float sum = 0.f;
        int kb = s0;

        f32x4 a0, a1, a2, a3;
        bool have = (kb + 8 <= s1);
        if (have) {
            long k = kb + hw;                  // rows k, k+2, k+4, k+6
            a0 = __builtin_nontemporal_load((const f32x4*)(K + (k + 0) * 128) + hl);
            a1 = __builtin_nontemporal_load((const f32x4*)(K + (k + 2) * 128) + hl);
            a2 = __builtin_nontemporal_load((const f32x4*)(K + (k + 4) * 128) + hl);
            a3 = __builtin_nontemporal_load((const f32x4*)(K + (k + 6) * 128) + hl);
        }
        while (have) {
            bool havenext = (kb + 16 <= s1);
            f32x4 b0v, b1v, b2v, b3v;
            if (havenext) {                    // issue next batch NOW
                long kn = kb + 8 + hw;
                b0v = __builtin_nontemporal_load((const f32x4*)(K + (kn + 0) * 128) + hl);
                b1v = __builtin_nontemporal_load((const f32x4*)(K + (kn + 2) * 128) + hl);
                b2v = __builtin_nontemporal_load((const f32x4*)(K + (kn + 4) * 128) + hl);
                b3v = __builtin_nontemporal_load((const f32x4*)(K + (kn + 6) * 128) + hl);
            }
            float v0 = dot4(a0, rfrag);
            float v1 = dot4(a1, rfrag);
            float v2 = dot4(a2, rfrag);
            float v3 = dot4(a3, rfrag);
#pragma unroll
            for (int off = 16; off > 0; off >>= 1) {
                v0 += __shfl_xor(v0, off, 64);
                v1 += __shfl_xor(v1, off, 64);
                v2 += __shfl_xor(v2, off, 64);
                v3 += __shfl_xor(v3, off, 64);
            }
            v0 *= sc; v1 *= sc; v2 *= sc; v3 *= sc;
            long k = kb + hw;
            if (hl == 0) {
                scores[k + 0] = v0;
                scores[k + 2] = v1;
                scores[k + 4] = v2;
                scores[k + 6] = v3;
            }
            float bm = fmaxf(fmaxf(v0, v1), fmaxf(v2, v3));
            float nm = fmaxf(mx, bm);
            sum = sum * __expf(mx - nm)
                + __expf(v0 - nm) + __expf(v1 - nm)
                + __expf(v2 - nm) + __expf(v3 - nm);
            mx = nm;
            kb += 8;
            a0 = b0v; a1 = b1v; a2 = b2v; a3 = b3v;
            have = havenext;
        }
        for (long k = kb + hw; k < s1; k += 2) {   // tail (<8 keys)
            f32x4 kv = __builtin_nontemporal_load((const f32x4*)(K + k * 128) + hl);
            float v = dot4(kv, rfrag);
#pragma unroll
            for (int off = 16; off > 0; off >>= 1) v += __shfl_xor(v, off, 64);
            v *= sc;
            if (hl == 0) scores[k] = v;
            float nm = fmaxf(mx, v);
            sum = sum * __expf(mx - nm) + __expf(v - nm);
            mx = nm;
        }
        // combine the two half-waves' (mx,sum)
        float mo = __shfl_xor(mx, 32, 64);
        float so = __shfl_xor(sum, 32, 64);
        float nm = fmaxf(mx, mo);
        sum = sum * __expf(mx - nm) + so * __expf(mo - nm);
        mx = nm;
        float inv = 1.0f / sum;

        // make this wave's score stores visible before re-reading
        asm volatile("s_waitcnt vmcnt(0)" ::: "memory");

        // weights from L1-hot scores
        for (int i = s0 + lane; i < s1; i += 64)
            weights[i] = __expf(scores[i] - mx) * inv;
    }
}

// ---------------------------------------------------------------------------
extern "C" void kernel_launch(void* const* d_in, const int* in_sizes, int n_in,
                              void* d_out, int out_size, void* d_ws, size_t ws_size,
                              hipStream_t stream) {
    const float* Q   = (const float*)d_in[0];
    const float* K   = (const float*)d_in[1];
    const float* WQ  = (const float*)d_in[2];
    const float* WK  = (const float*)d_in[3];
    const int*   idx = (const int*)d_in[4];

    const int nmols = in_sizes[0] / QUERY_DIM;   // 16384
    const int total = in_sizes[4];               // 1048576

    float* weights = (float*)d_out;              // output 0
    float* scores  = (float*)d_out + total;      // output 1

    char* ws = (char*)d_ws;
    float* W        = (float*)ws;                // 64 KB
    int*   segstart = (int*)(ws + 65536);        // (nmols+1)*4

    int segblocks = (nmols + 1 + 255) / 256;
    combo_kernel<<<64 + segblocks, 256, 0, stream>>>(WQ, WK, W, idx, segstart, nmols, total);
    // waves = 2048*256/64 = 8192; wave w owns segments 2w, 2w+1
    fused2_kernel<<<2048, 256, 0, stream>>>(Q, W, K, segstart, weights, scores, nmols, total);
}

// Round 12
// 130.610 us; speedup vs baseline: 1.8595x; 1.2135x over previous
//
#include <hip/hip_runtime.h>
#include <hip/hip_bf16.h>

#define QUERY_DIM 128
#define HIDDEN 128

typedef float f32x4 __attribute__((ext_vector_type(4)));

__device__ __forceinline__ float dot4(f32x4 a, f32x4 b) {
    return a.x * b.x + a.y * b.y + a.z * b.z + a.w * b.w;
}

// ---------------------------------------------------------------------------
// Kernel 1: W[e][d] = sum_h WQ[h][e] * WK[h][d]   (128x128, tiny)
// ---------------------------------------------------------------------------
__global__ void wqk_kernel(const float* __restrict__ WQ,
                           const float* __restrict__ WK,
                           float* __restrict__ W) {
    int e = blockIdx.x;    // 0..127
    int d = threadIdx.x;   // 0..127
    float acc = 0.f;
#pragma unroll 8
    for (int h = 0; h < HIDDEN; ++h) {
        acc += WQ[h * QUERY_DIM + e] * WK[h * 128 + d];
    }
    W[e * 128 + d] = acc;
}

// ---------------------------------------------------------------------------
// Kernel 2 (qproj2 + segstart): blocks [0, qblocks) do R = Q @ W with
// 8-row x 4-col register blocking: 64 rows/block, thread t owns cols
// [4*(t&31), +4) for rows [8*(t>>5), +8). Per 4-d tile: 4 b128 W reads
// (per-lane) + 8 b128 Q reads (half-wave broadcast, free) = 1.5 B/FMA of
// LDS traffic (was 4.5). Blocks [qblocks, ...) do segment-start binary
// search. LDS = 32K wl + 32K ql = 64 KB (1 block/CU; grid==CU count).
// ---------------------------------------------------------------------------
__global__ __launch_bounds__(256) void qproj2_kernel(const float* __restrict__ Q,
                                                     const float* __restrict__ W,
                                                     float* __restrict__ R,
                                                     const int* __restrict__ idx,
                                                     int* __restrict__ start,
                                                     int nmols, int total, int qblocks) {
    int b = blockIdx.x;
    int t = threadIdx.x;
    if (b >= qblocks) {
        // ---- segment starts via binary search (idx sorted) ----
        int m = (b - qblocks) * 256 + t;
        if (m > nmols) return;
        if (m == nmols) { start[m] = total; return; }
        int lo = 0, hi = total;
        while (lo < hi) {
            int mid = (lo + hi) >> 1;
            if (idx[mid] < m) lo = mid + 1; else hi = mid;
        }
        start[m] = lo;
        return;
    }

    __shared__ float wl[64 * 128];   // 32 KB: half of W
    __shared__ float ql[64 * 128];   // 32 KB: 64 Q rows
    const int c4 = (t & 31) * 4;     // 4 contiguous columns
    const int g  = t >> 5;           // row-group: rows g*8 .. g*8+7
    const long row0 = (long)b * 64;

    // stage 64 Q rows (8192 floats, clamped for generality)
    for (int i = t * 4; i < 64 * 128; i += 256 * 4) {
        long rr = row0 + (i >> 7);
        if (rr > nmols - 1) rr = nmols - 1;
        *(f32x4*)&ql[i] = *(const f32x4*)&Q[rr * 128 + (i & 127)];
    }

    f32x4 acc[8];
#pragma unroll
    for (int r = 0; r < 8; ++r) acc[r] = (f32x4){0.f, 0.f, 0.f, 0.f};

    for (int hf = 0; hf < 2; ++hf) {
        __syncthreads();
        for (int i = t * 4; i < 64 * 128; i += 256 * 4) {
            *(f32x4*)&wl[i] = *(const f32x4*)&W[hf * 64 * 128 + i];
        }
        __syncthreads();
        for (int d = 0; d < 64; d += 4) {
            f32x4 w0 = *(const f32x4*)&wl[(d + 0) * 128 + c4];
            f32x4 w1 = *(const f32x4*)&wl[(d + 1) * 128 + c4];
            f32x4 w2 = *(const f32x4*)&wl[(d + 2) * 128 + c4];
            f32x4 w3 = *(const f32x4*)&wl[(d + 3) * 128 + c4];
            int dg = hf * 64 + d;
#pragma unroll
            for (int r = 0; r < 8; ++r) {
                f32x4 q = *(const f32x4*)&ql[(g * 8 + r) * 128 + dg];  // broadcast
                acc[r] += q.x * w0 + q.y * w1 + q.z * w2 + q.w * w3;
            }
        }
    }
#pragma unroll
    for (int r = 0; r < 8; ++r) {
        long row = row0 + g * 8 + r;
        if (row < nmols) *(f32x4*)&R[row * 128 + c4] = acc[r];
    }
}

// ---------------------------------------------------------------------------
// Kernel 3 (fused, dominant) — R7 version verbatim (best measured: 137.7).
// One wave per segment (grid-stride); half-wave per key row (512B);
// phase 1 unrolled x4 (4 independent 1KB wave-loads in flight).
// ---------------------------------------------------------------------------
__global__ __launch_bounds__(256) void fused_kernel(const float* __restrict__ K,
                                                    const float* __restrict__ R,
                                                    const int* __restrict__ start,
                                                    float* __restrict__ weights,
                                                    float* scores,   // no restrict: store+load alias
                                                    int nmols) {
    const int lane = threadIdx.x & 63;
    const int half = lane >> 5;      // 0/1
    const int hl = lane & 31;        // lane within half-wave
    const int wave = (blockIdx.x * 256 + threadIdx.x) >> 6;
    const int nwaves = gridDim.x * 4;
    const float sc = 0.08838834764831845f;  // 1/sqrt(128)

    for (int s = wave; s < nmols; s += nwaves) {
        int s0 = start[s], s1 = start[s + 1];
        if (s0 >= s1) continue;

        f32x4 rfrag = *((const f32x4*)(R + (long)s * 128) + hl);

        // ---- phase 1: scores + running max ----
        float mx = -__builtin_inff();
        int kb = s0;
        for (; kb + 8 <= s1; kb += 8) {
            long k = kb + half;          // this half: rows k, k+2, k+4, k+6
            const f32x4* p0 = (const f32x4*)(K + (k + 0) * 128) + hl;
            const f32x4* p1 = (const f32x4*)(K + (k + 2) * 128) + hl;
            const f32x4* p2 = (const f32x4*)(K + (k + 4) * 128) + hl;
            const f32x4* p3 = (const f32x4*)(K + (k + 6) * 128) + hl;
            f32x4 a0 = __builtin_nontemporal_load(p0);
            f32x4 a1 = __builtin_nontemporal_load(p1);
            f32x4 a2 = __builtin_nontemporal_load(p2);
            f32x4 a3 = __builtin_nontemporal_load(p3);
            float v0 = dot4(a0, rfrag);
            float v1 = dot4(a1, rfrag);
            float v2 = dot4(a2, rfrag);
            float v3 = dot4(a3, rfrag);
#pragma unroll
            for (int off = 16; off > 0; off >>= 1) {
                v0 += __shfl_xor(v0, off, 64);
                v1 += __shfl_xor(v1, off, 64);
                v2 += __shfl_xor(v2, off, 64);
                v3 += __shfl_xor(v3, off, 64);
            }
            v0 *= sc; v1 *= sc; v2 *= sc; v3 *= sc;
            if (hl == 0) {
                scores[k + 0] = v0;
                scores[k + 2] = v1;
                scores[k + 4] = v2;
                scores[k + 6] = v3;
            }
            mx = fmaxf(mx, fmaxf(fmaxf(v0, v1), fmaxf(v2, v3)));
        }
        for (long k = kb + half; k < s1; k += 2) {   // tail (<8 keys)
            f32x4 kv = __builtin_nontemporal_load((const f32x4*)(K + k * 128) + hl);
            float v = dot4(kv, rfrag);
#pragma unroll
            for (int off = 16; off > 0; off >>= 1) v += __shfl_xor(v, off, 64);
            v *= sc;
            if (hl == 0) scores[k] = v;
            mx = fmaxf(mx, v);
        }
        mx = fmaxf(mx, __shfl_xor(mx, 32, 64));

        // make the scores stores visible before re-reading
        asm volatile("s_waitcnt vmcnt(0)" ::: "memory");

        // ---- phase 2: sum of exp (scores L1-hot) ----
        float sum = 0.f;
        for (int i = s0 + lane; i < s1; i += 64) sum += __expf(scores[i] - mx);
#pragma unroll
        for (int off = 32; off > 0; off >>= 1) sum += __shfl_xor(sum, off, 64);
        float inv = 1.0f / sum;

        // ---- phase 3: weights ----
        for (int i = s0 + lane; i < s1; i += 64)
            weights[i] = __expf(scores[i] - mx) * inv;
    }
}

// ---------------------------------------------------------------------------
extern "C" void kernel_launch(void* const* d_in, const int* in_sizes, int n_in,
                              void* d_out, int out_size, void* d_ws, size_t ws_size,
                              hipStream_t stream) {
    const float* Q   = (const float*)d_in[0];
    const float* K   = (const float*)d_in[1];
    const float* WQ  = (const float*)d_in[2];
    const float* WK  = (const float*)d_in[3];
    const int*   idx = (const int*)d_in[4];

    const int nmols = in_sizes[0] / QUERY_DIM;   // 16384
    const int total = in_sizes[4];               // 1048576

    float* weights = (float*)d_out;              // output 0
    float* scores  = (float*)d_out + total;      // output 1

    char* ws = (char*)d_ws;
    float* W        = (float*)ws;                        // 64 KB
    int*   segstart = (int*)(ws + 65536);                // (nmols+1)*4
    float* R        = (float*)(ws + 65536 + 131072);     // nmols*128*4 = 8 MB

    wqk_kernel<<<128, 128, 0, stream>>>(WQ, WK, W);
    int qblocks  = (nmols + 63) / 64;            // 256
    int segblocks = (nmols + 1 + 255) / 256;     // 65
    qproj2_kernel<<<qblocks + segblocks, 256, 0, stream>>>(Q, W, R, idx, segstart,
                                                           nmols, total, qblocks);
    fused_kernel<<<2048, 256, 0, stream>>>(K, R, segstart, weights, scores, nmols);
}